// Round 4
// baseline (7317.174 us; speedup 1.0000x reference)
//
#include <hip/hip_runtime.h>
#include <hip/hip_bf16.h>

// Problem dims
#define SEQ   2048
#define BATCH 16
#define DIN   512
#define HID   512
#define MROWS (SEQ*BATCH)   // 32768 GEMM rows (s,b)
#define KDIM  DIN           // 512

// Chunking: one 128-row m-tile = 8 timesteps x 16 batches = one scan chunk
#define NCH   256           // chunks along S (SEQ/8)
#define NGRP  32            // scan groups = 2 dir x 16 h-tiles
#define SENT32 0x7f7f7f7fu  // memset(0x7F) sentinel; impossible as A in [0,1] or |H|<~2

typedef unsigned short u16;
typedef unsigned long long u64;
typedef __bf16 bf16x8 __attribute__((ext_vector_type(8)));
typedef float  f32x4  __attribute__((ext_vector_type(4)));

__device__ __forceinline__ unsigned f2bf(float x) {
  unsigned u = __float_as_uint(x);
  return (u + 0x7fffu + ((u >> 16) & 1u)) >> 16;   // RNE
}

__device__ __forceinline__ void async_ld16(const void* g, void* l) {
  __builtin_amdgcn_global_load_lds(
      (const __attribute__((address_space(1))) void*)g,
      (__attribute__((address_space(3))) void*)l, 16, 0, 0);
}

__device__ __forceinline__ float sig_fast(float x) {
  return __builtin_amdgcn_rcpf(1.f + __expf(-x));
}
__device__ __forceinline__ float tanh_fast(float x) {
  return 1.f - 2.f * __builtin_amdgcn_rcpf(1.f + __expf(2.f * x));
}

// ---- merged fp32 -> bf16 conversion: X (16384 blocks), Wfw (768), Wbw (768) ----
__global__ void cvt_all(const float* __restrict__ X, const float* __restrict__ Wfw,
                        const float* __restrict__ Wbw,
                        u16* __restrict__ Xb, u16* __restrict__ Wb) {
  const int tid = threadIdx.x;
  const int bid = blockIdx.x;
  const float* src; u16* dst; int idx;
  if (bid < 16384)      { src = X;   dst = Xb;                          idx = bid * 256 + tid; }
  else if (bid < 17152) { src = Wfw; dst = Wb;                          idx = (bid - 16384) * 256 + tid; }
  else                  { src = Wbw; dst = Wb + 3 * HID * KDIM;         idx = (bid - 17152) * 256 + tid; }
  const float4 v = ((const float4*)src)[idx];
  uint2 r;
  r.x = f2bf(v.x) | (f2bf(v.y) << 16);
  r.y = f2bf(v.z) | (f2bf(v.w) << 16);
  ((uint2*)dst)[idx] = r;
}

// ---- Fused GEMM + gates + intra-chunk scan + decoupled-lookback carry + output ----
// Ticket-ordered tiles: ticket = cs*32 + g; g = (dir, h-tile); cs = time-chunk index.
// Block: 128 m-rows (8 s x 16 b) x 96 n (3 gates x 32 h).  Wave (2m x 2p): 64m x 48n.
// Epilogue: in-lane 4-step scan + cross-wave combine -> chunk-local (H,P) prefixes;
// publish chunk aggregate (A,C) as one 64-bit agent atomic; lookback over earlier
// chunks of the same group (ticket order => predecessors already started =>
// deadlock-free); publish inclusive prefix; write out = o*(H + P*carry) fp32.
__launch_bounds__(256, 5)
__global__ void gemm_fused_scan(const u16* __restrict__ A, const u16* __restrict__ B,
                                const float* __restrict__ bfw, const float* __restrict__ bbw,
                                float* __restrict__ out,
                                u64* __restrict__ agg, unsigned* __restrict__ pfx,
                                int* __restrict__ cnt)
{
  __shared__ __align__(16) u16 sA[128 * 64];   // 16 KB (reused for epilogue exchange)
  __shared__ __align__(16) u16 sB[96 * 64];    // 12 KB
  __shared__ int s_ticket;

  const int t    = threadIdx.x;
  const int wave = t >> 6;
  const int lane = t & 63;

  if (t == 0) s_ticket = atomicAdd(cnt, 1);
  __syncthreads();
  const int ticket = s_ticket;
  const int g   = ticket & 31;          // scan group
  const int cs  = ticket >> 5;          // time-chunk index 0..255
  const int dir = g >> 4;
  const int hb  = (g & 15) * 32;
  const int m0  = (dir ? (NCH - 1 - cs) : cs) * 128;

  const int wm  = (wave >> 1) * 64;     // m half
  const int p   = wave & 1;             // n half (h-sub-tile of 16)
  const int wn  = p * 48;

  f32x4 acc[4][3] = {};

  // staging: lane -> (rloc = lane>>3, c = lane&7); global 16B chunk gc = c ^ rloc
  const int rloc = lane >> 3;
  const int gch  = (lane & 7) ^ rloc;
  const u16* gA  = A + (size_t)(m0 + wave * 32 + rloc) * KDIM + gch * 8;
  const u16* WbD = B + (size_t)dir * (3 * HID * KDIM);
  unsigned gBo[3];
#pragma unroll
  for (int j = 0; j < 3; j++) {
    const int nl = wave * 24 + j * 8 + rloc;      // 0..95
    const int pp = nl >= 48 ? 1 : 0;
    const int r  = nl - pp * 48;
    const int wrow = (r >> 4) * HID + hb + pp * 16 + (r & 15);
    gBo[j] = (unsigned)(wrow * KDIM + gch * 8);
  }

  const int lm = lane & 15;            // fragment index (= batch b for A rows)
  const int q  = lane >> 4;            // k-quad / n-reg group
  const int xs = lm & 7;               // read-side swizzle = row&7

  for (int kt = 0; kt < KDIM; kt += 64) {
    __syncthreads();
#pragma unroll
    for (int j = 0; j < 4; j++)
      async_ld16(gA + kt + (size_t)(j * 8) * KDIM, sA + (wave * 32 + j * 8) * 64);
#pragma unroll
    for (int j = 0; j < 3; j++)
      async_ld16(WbD + gBo[j] + kt, sB + (wave * 24 + j * 8) * 64);
    __syncthreads();

#pragma unroll
    for (int s = 0; s < 2; s++) {
      const int cofs = ((s * 4 + q) ^ xs) * 8;
      bf16x8 af[4], bfr[3];
#pragma unroll
      for (int mi = 0; mi < 4; mi++)
        af[mi] = *(const bf16x8*)(sA + (wm + mi * 16 + lm) * 64 + cofs);
#pragma unroll
      for (int ni = 0; ni < 3; ni++)
        bfr[ni] = *(const bf16x8*)(sB + (wn + ni * 16 + lm) * 64 + cofs);
#pragma unroll
      for (int mi = 0; mi < 4; mi++)
#pragma unroll
        for (int ni = 0; ni < 3; ni++)  // swapped: D col=lane&15 (m), row=q*4+i (n)
          acc[mi][ni] = __builtin_amdgcn_mfma_f32_16x16x32_bf16(bfr[ni], af[mi], acc[mi][ni], 0, 0, 0);
    }
  }

  // ---- epilogue ----
  // lane holds: m = m0 + wm + mi*16 + lm  (b = lm, s_local = (wave>>1)*4 + mi)
  //             h = hb + p*16 + q*4 + e, gate = ni
  const float* bias = dir ? bbw : bfw;
  const int hcol0 = hb + p * 16 + q * 4;

  const float4 t0 = *(const float4*)(bias + 0 * HID + hcol0);
  const float4 t1 = *(const float4*)(bias + 1 * HID + hcol0);
  const float4 t2 = *(const float4*)(bias + 2 * HID + hcol0);
  f32x4 bz, bff, bo;
  bz[0] = t0.x; bz[1] = t0.y; bz[2] = t0.z; bz[3] = t0.w;
  bff[0] = t1.x; bff[1] = t1.y; bff[2] = t1.z; bff[3] = t1.w;
  bo[0] = t2.x; bo[1] = t2.y; bo[2] = t2.z; bo[3] = t2.w;

  // activations in place: acc[mi][0] = c = f*z ; acc[mi][1] = a = 1-f ; acc[mi][2] = o
#pragma unroll
  for (int mi = 0; mi < 4; mi++)
#pragma unroll
    for (int e = 0; e < 4; e++) {
      const float z = tanh_fast(acc[mi][0][e] + bz[e]);
      const float f = sig_fast(acc[mi][1][e] + bff[e]);
      const float o = sig_fast(acc[mi][2][e] + bo[e]);
      acc[mi][0][e] = f * z;
      acc[mi][1][e] = 1.f - f;
      acc[mi][2][e] = o;
    }

  // in-lane 4-step scan in TIME order (fw: mi 0->3, bw: mi 3->0), in place:
  // acc[mi][0] <- H_step(mi), acc[mi][1] <- P_step(mi)   (static indices only)
#define SCAN_STEP(MI) { const f32x4 a_ = acc[MI][1], c_ = acc[MI][0]; \
    Hc = a_ * Hc + c_; Pc = a_ * Pc; acc[MI][0] = Hc; acc[MI][1] = Pc; }
  {
    f32x4 Hc = {0.f, 0.f, 0.f, 0.f}, Pc = {1.f, 1.f, 1.f, 1.f};
    if (!dir) { SCAN_STEP(0) SCAN_STEP(1) SCAN_STEP(2) SCAN_STEP(3) }
    else      { SCAN_STEP(3) SCAN_STEP(2) SCAN_STEP(1) SCAN_STEP(0) }
  }
#undef SCAN_STEP

  // cross-wave combine: time-first half publishes its 4-step (P,H); the other
  // half prefixes with it.  fw: first = wm-half 0 (s_local 0..3); bw: wm-half 1.
  __syncthreads();                       // all K-loop LDS reads done -> reuse sA
  f32x4* ex = (f32x4*)sA;                // bytes [0, 4096): [2p][64 lanes][2]
  const int slot = p * 64 + lane;
  const bool firstHalf = ((wave >> 1) == (dir ? 1 : 0));
  if (firstHalf) {
    ex[slot * 2 + 0] = dir ? acc[0][1] : acc[3][1];   // P
    ex[slot * 2 + 1] = dir ? acc[0][0] : acc[3][0];   // H
  }
  __syncthreads();
  if (!firstHalf) {
    const f32x4 P0 = ex[slot * 2 + 0];
    const f32x4 H0 = ex[slot * 2 + 1];
#pragma unroll
    for (int mi = 0; mi < 4; mi++) {
      acc[mi][0] = acc[mi][0] + acc[mi][1] * H0;
      acc[mi][1] = acc[mi][1] * P0;
    }
  }

  // ---- decoupled lookback for the cross-chunk carry ----
  const int slotbase = lm * 32 + p * 16 + q * 4;   // this thread's 4 seqs within block
  float* cr = (float*)sA + 1024;                   // bytes [4096, 6144): 512-float carry
  const f32x4 Pf = dir ? acc[0][1] : acc[3][1];    // full-chunk transform (valid in last half)
  const f32x4 Hf = dir ? acc[0][0] : acc[3][0];

  if (!firstHalf) {
    // publish chunk aggregate (A=Pf, C=Hf) as single 64-bit release atomics
    u64* aggS = agg + (size_t)ticket * 512 + slotbase;
#pragma unroll
    for (int e = 0; e < 4; e++) {
      const u64 v = ((u64)__float_as_uint(Hf[e]) << 32) | (u64)__float_as_uint(Pf[e]);
      __hip_atomic_store(aggS + e, v, __ATOMIC_RELEASE, __HIP_MEMORY_SCOPE_AGENT);
    }
    // walk back over earlier chunks of this group
    float carry[4] = {0.f, 0.f, 0.f, 0.f};
    float cA[4] = {1.f, 1.f, 1.f, 1.f};
    float cC[4] = {0.f, 0.f, 0.f, 0.f};
    unsigned doneMask = (cs == 0) ? 0xFu : 0u;
    for (int i = cs - 1; i >= 0 && doneMask != 0xFu; --i) {
      const size_t slab = ((size_t)i * NGRP + g) * 512 + slotbase;
      const unsigned* pfxP = pfx + slab;
      const u64*      aggP = agg + slab;
#pragma unroll
      for (int e = 0; e < 4; e++) {
        if (doneMask & (1u << e)) continue;
        int guard = 0;
        for (;;) {
          const unsigned pv = __hip_atomic_load(pfxP + e, __ATOMIC_ACQUIRE, __HIP_MEMORY_SCOPE_AGENT);
          if (pv != SENT32) {          // inclusive prefix available: finish
            carry[e] = fmaf(cA[e], __uint_as_float(pv), cC[e]);
            doneMask |= 1u << e;
            break;
          }
          const u64 av = __hip_atomic_load(aggP + e, __ATOMIC_ACQUIRE, __HIP_MEMORY_SCOPE_AGENT);
          if ((unsigned)av != SENT32) {  // aggregate: fold, continue to i-1
            const float Ai = __uint_as_float((unsigned)av);
            const float Ci = __uint_as_float((unsigned)(av >> 32));
            cC[e] = fmaf(cA[e], Ci, cC[e]);
            cA[e] *= Ai;
            break;
          }
          if (++guard > (1 << 23)) { carry[e] = cC[e]; doneMask |= 1u << e; break; }
          __builtin_amdgcn_s_sleep(1);
        }
      }
    }
#pragma unroll
    for (int e = 0; e < 4; e++)
      if (!(doneMask & (1u << e))) carry[e] = cC[e];   // walked to chunk 0: h_init = 0

    // publish inclusive prefix and share carry with the other half
    unsigned* pfxS = pfx + (size_t)ticket * 512 + slotbase;
#pragma unroll
    for (int e = 0; e < 4; e++) {
      const float hp = fmaf(Pf[e], carry[e], Hf[e]);
      __hip_atomic_store(pfxS + e, __float_as_uint(hp), __ATOMIC_RELEASE, __HIP_MEMORY_SCOPE_AGENT);
      cr[slotbase + e] = carry[e];
    }
  }
  __syncthreads();

  f32x4 cl;
  cl[0] = cr[slotbase + 0]; cl[1] = cr[slotbase + 1];
  cl[2] = cr[slotbase + 2]; cl[3] = cr[slotbase + 3];

  // out = o * (H_local + P_local * carry), fp32, direct
#pragma unroll
  for (int mi = 0; mi < 4; mi++) {
    const f32x4 hg = acc[mi][0] + acc[mi][1] * cl;
    const f32x4 ov = acc[mi][2] * hg;
    float* ob = out + (size_t)(m0 + wm + mi * 16 + lm) * (2 * HID) + dir * HID + hcol0;
    __builtin_nontemporal_store(ov, (f32x4*)ob);
  }
}

extern "C" void kernel_launch(void* const* d_in, const int* in_sizes, int n_in,
                              void* d_out, int out_size, void* d_ws, size_t ws_size,
                              hipStream_t stream) {
  const float* X   = (const float*)d_in[0];
  const float* Wfw = (const float*)d_in[1];
  const float* bfw = (const float*)d_in[2];
  const float* Wbw = (const float*)d_in[3];
  const float* bbw = (const float*)d_in[4];
  float* out = (float*)d_out;

  char* ws = (char*)d_ws;
  const size_t XB   = (size_t)MROWS * KDIM * 2;            // 32 MiB
  const size_t WB   = (size_t)2 * 3 * HID * KDIM * 2;      // 3 MiB
  const size_t AGGB = (size_t)NCH * NGRP * 512 * 8;        // 32 MiB
  const size_t PFXB = (size_t)NCH * NGRP * 512 * 4;        // 16 MiB
  u16*      Xb  = (u16*)ws;
  u16*      Wb  = (u16*)(ws + XB);
  u64*      agg = (u64*)(ws + XB + WB);
  unsigned* pfx = (unsigned*)(ws + XB + WB + AGGB);
  int*      cnt = (int*)(ws + XB + WB + AGGB + PFXB);

  // sentinel-fill lookback slabs (0x7F7F7F7F impossible as A or H), zero ticket
  hipMemsetAsync(agg, 0x7F, AGGB + PFXB, stream);
  hipMemsetAsync(cnt, 0, 256, stream);

  // bf16 conversions (X + both W) in one launch
  cvt_all<<<17920, 256, 0, stream>>>(X, Wfw, Wbw, Xb, Wb);

  // fully fused GEMM + gates + scan + output: 8192 ticket-ordered blocks
  gemm_fused_scan<<<NCH * NGRP, 256, 0, stream>>>(Xb, Wb, bfw, bbw, out, agg, pfx, cnt);
}

// Round 5
// 1753.327 us; speedup vs baseline: 4.1733x; 4.1733x over previous
//
#include <hip/hip_runtime.h>
#include <hip/hip_bf16.h>

// Problem dims
#define SEQ   2048
#define BATCH 16
#define DIN   512
#define HID   512
#define MROWS (SEQ*BATCH)   // 32768 GEMM rows (s,b)
#define KDIM  DIN           // 512

// Chunking: one 128-row m-tile = 8 timesteps x 16 batches = one scan chunk
#define NCH   256           // chunks along S (SEQ/8)
#define NGRP  32            // scan groups = 2 dir x 16 h-tiles
#define LOOKBACK_LIM (1 << 22)

typedef unsigned short u16;
typedef __bf16 bf16x8 __attribute__((ext_vector_type(8)));
typedef float  f32x4  __attribute__((ext_vector_type(4)));

__device__ __forceinline__ unsigned f2bf(float x) {
  unsigned u = __float_as_uint(x);
  return (u + 0x7fffu + ((u >> 16) & 1u)) >> 16;   // RNE
}

__device__ __forceinline__ void async_ld16(const void* g, void* l) {
  __builtin_amdgcn_global_load_lds(
      (const __attribute__((address_space(1))) void*)g,
      (__attribute__((address_space(3))) void*)l, 16, 0, 0);
}

__device__ __forceinline__ float sig_fast(float x) {
  return __builtin_amdgcn_rcpf(1.f + __expf(-x));
}
__device__ __forceinline__ float tanh_fast(float x) {
  return 1.f - 2.f * __builtin_amdgcn_rcpf(1.f + __expf(2.f * x));
}

// ---- merged fp32 -> bf16 conversion: X (16384 blocks), Wfw (768), Wbw (768) ----
__global__ void cvt_all(const float* __restrict__ X, const float* __restrict__ Wfw,
                        const float* __restrict__ Wbw,
                        u16* __restrict__ Xb, u16* __restrict__ Wb) {
  const int tid = threadIdx.x;
  const int bid = blockIdx.x;
  const float* src; u16* dst; int idx;
  if (bid < 16384)      { src = X;   dst = Xb;                  idx = bid * 256 + tid; }
  else if (bid < 17152) { src = Wfw; dst = Wb;                  idx = (bid - 16384) * 256 + tid; }
  else                  { src = Wbw; dst = Wb + 3 * HID * KDIM; idx = (bid - 17152) * 256 + tid; }
  const float4 v = ((const float4*)src)[idx];
  uint2 r;
  r.x = f2bf(v.x) | (f2bf(v.y) << 16);
  r.y = f2bf(v.z) | (f2bf(v.w) << 16);
  ((uint2*)dst)[idx] = r;
}

// ---- Fused GEMM + gates + intra-chunk scan + block-granular lookback + output ----
// Ticket-ordered tiles: ticket = cs*32 + g; g = (dir, h-tile); cs = time-chunk index.
// Block: 128 m-rows (8 s x 16 b) x 96 n (3 gates x 32 h).  Wave (2m x 2p): 64m x 48n.
// Lookback protocol (per ticket): flg 0=empty, 1=aggregate ready, 2=prefix ready.
// Payload via relaxed agent atomics (coherent point), flag via release/acquire.
// ONE flag address per block -> polls are wave-coalesced (no fabric storm).
__launch_bounds__(256, 5)
__global__ void gemm_fused_scan(const u16* __restrict__ A, const u16* __restrict__ B,
                                const float* __restrict__ bfw, const float* __restrict__ bbw,
                                float* __restrict__ out,
                                float* __restrict__ aggA, float* __restrict__ aggC,
                                float* __restrict__ pfxH, unsigned* __restrict__ flg,
                                int* __restrict__ cnt)
{
  __shared__ __align__(16) u16 sA[128 * 64];   // 16 KB (reused for epilogue exchange)
  __shared__ __align__(16) u16 sB[96 * 64];    // 12 KB
  __shared__ int s_ticket;

  const int t    = threadIdx.x;
  const int wave = t >> 6;
  const int lane = t & 63;

  if (t == 0) s_ticket = atomicAdd(cnt, 1);
  __syncthreads();
  const int ticket = s_ticket;
  const int g   = ticket & 31;          // scan group
  const int cs  = ticket >> 5;          // time-chunk index 0..255
  const int dir = g >> 4;
  const int hb  = (g & 15) * 32;
  const int m0  = (dir ? (NCH - 1 - cs) : cs) * 128;

  const int wm  = (wave >> 1) * 64;     // m half
  const int p   = wave & 1;             // n half (h-sub-tile of 16)
  const int wn  = p * 48;

  f32x4 acc[4][3] = {};

  // staging: lane -> (rloc = lane>>3, c = lane&7); global 16B chunk gc = c ^ rloc
  const int rloc = lane >> 3;
  const int gch  = (lane & 7) ^ rloc;
  const u16* gA  = A + (size_t)(m0 + wave * 32 + rloc) * KDIM + gch * 8;
  const u16* WbD = B + (size_t)dir * (3 * HID * KDIM);
  unsigned gBo[3];
#pragma unroll
  for (int j = 0; j < 3; j++) {
    const int nl = wave * 24 + j * 8 + rloc;      // 0..95
    const int pp = nl >= 48 ? 1 : 0;
    const int r  = nl - pp * 48;
    const int wrow = (r >> 4) * HID + hb + pp * 16 + (r & 15);
    gBo[j] = (unsigned)(wrow * KDIM + gch * 8);
  }

  const int lm = lane & 15;            // fragment index (= batch b for A rows)
  const int q  = lane >> 4;            // k-quad / n-reg group
  const int xs = lm & 7;               // read-side swizzle = row&7

  for (int kt = 0; kt < KDIM; kt += 64) {
    __syncthreads();
#pragma unroll
    for (int j = 0; j < 4; j++)
      async_ld16(gA + kt + (size_t)(j * 8) * KDIM, sA + (wave * 32 + j * 8) * 64);
#pragma unroll
    for (int j = 0; j < 3; j++)
      async_ld16(WbD + gBo[j] + kt, sB + (wave * 24 + j * 8) * 64);
    __syncthreads();

#pragma unroll
    for (int s = 0; s < 2; s++) {
      const int cofs = ((s * 4 + q) ^ xs) * 8;
      bf16x8 af[4], bfr[3];
#pragma unroll
      for (int mi = 0; mi < 4; mi++)
        af[mi] = *(const bf16x8*)(sA + (wm + mi * 16 + lm) * 64 + cofs);
#pragma unroll
      for (int ni = 0; ni < 3; ni++)
        bfr[ni] = *(const bf16x8*)(sB + (wn + ni * 16 + lm) * 64 + cofs);
#pragma unroll
      for (int mi = 0; mi < 4; mi++)
#pragma unroll
        for (int ni = 0; ni < 3; ni++)  // swapped: D col=lane&15 (m), row=q*4+i (n)
          acc[mi][ni] = __builtin_amdgcn_mfma_f32_16x16x32_bf16(bfr[ni], af[mi], acc[mi][ni], 0, 0, 0);
    }
  }

  // ---- epilogue ----
  // lane holds: m = m0 + wm + mi*16 + lm  (b = lm, s_local = (wave>>1)*4 + mi)
  //             h = hb + p*16 + q*4 + e, gate = ni
  const float* bias = dir ? bbw : bfw;
  const int hcol0 = hb + p * 16 + q * 4;

  const float4 t0 = *(const float4*)(bias + 0 * HID + hcol0);
  const float4 t1 = *(const float4*)(bias + 1 * HID + hcol0);
  const float4 t2 = *(const float4*)(bias + 2 * HID + hcol0);
  f32x4 bz, bff, bo;
  bz[0] = t0.x; bz[1] = t0.y; bz[2] = t0.z; bz[3] = t0.w;
  bff[0] = t1.x; bff[1] = t1.y; bff[2] = t1.z; bff[3] = t1.w;
  bo[0] = t2.x; bo[1] = t2.y; bo[2] = t2.z; bo[3] = t2.w;

  // activations in place: acc[mi][0] = c = f*z ; acc[mi][1] = a = 1-f ; acc[mi][2] = o
#pragma unroll
  for (int mi = 0; mi < 4; mi++)
#pragma unroll
    for (int e = 0; e < 4; e++) {
      const float z = tanh_fast(acc[mi][0][e] + bz[e]);
      const float f = sig_fast(acc[mi][1][e] + bff[e]);
      const float o = sig_fast(acc[mi][2][e] + bo[e]);
      acc[mi][0][e] = f * z;
      acc[mi][1][e] = 1.f - f;
      acc[mi][2][e] = o;
    }

  // in-lane 4-step scan in TIME order (fw: mi 0->3, bw: mi 3->0), in place:
  // acc[mi][0] <- H_step(mi), acc[mi][1] <- P_step(mi)   (static indices only)
#define SCAN_STEP(MI) { const f32x4 a_ = acc[MI][1], c_ = acc[MI][0]; \
    Hc = a_ * Hc + c_; Pc = a_ * Pc; acc[MI][0] = Hc; acc[MI][1] = Pc; }
  {
    f32x4 Hc = {0.f, 0.f, 0.f, 0.f}, Pc = {1.f, 1.f, 1.f, 1.f};
    if (!dir) { SCAN_STEP(0) SCAN_STEP(1) SCAN_STEP(2) SCAN_STEP(3) }
    else      { SCAN_STEP(3) SCAN_STEP(2) SCAN_STEP(1) SCAN_STEP(0) }
  }
#undef SCAN_STEP

  // cross-wave combine: time-first half publishes its 4-step (P,H); the other
  // half prefixes with it.  fw: first = wm-half 0 (s_local 0..3); bw: wm-half 1.
  __syncthreads();                       // all K-loop LDS reads done -> reuse sA
  f32x4* ex = (f32x4*)sA;                // bytes [0, 4096): [2p][64 lanes][2]
  const int slot = p * 64 + lane;
  const bool firstHalf = ((wave >> 1) == (dir ? 1 : 0));
  if (firstHalf) {
    ex[slot * 2 + 0] = dir ? acc[0][1] : acc[3][1];   // P
    ex[slot * 2 + 1] = dir ? acc[0][0] : acc[3][0];   // H
  }
  __syncthreads();
  if (!firstHalf) {
    const f32x4 P0 = ex[slot * 2 + 0];
    const f32x4 H0 = ex[slot * 2 + 1];
#pragma unroll
    for (int mi = 0; mi < 4; mi++) {
      acc[mi][0] = acc[mi][0] + acc[mi][1] * H0;
      acc[mi][1] = acc[mi][1] * P0;
    }
  }

  // ---- block-granular decoupled lookback ----
  const int sb  = lm * 32 + p * 16 + q * 4;        // element base within block's 512 seqs
  const int crb = lm * 33 + p * 16 + q * 4;        // LDS carry slab, stride-33 (bank-spread)
  float* cr = (float*)sA + 1024;                   // bytes [4096, 6304)

  const f32x4 Pf = dir ? acc[0][1] : acc[3][1];    // full-chunk transform (valid in lastHalf)
  const f32x4 Hf = dir ? acc[0][0] : acc[3][0];

  // 1) publish aggregate payload (relaxed agent atomics -> coherent point)
  if (!firstHalf) {
    float* aS = aggA + (size_t)ticket * 512 + sb;
    float* cS = aggC + (size_t)ticket * 512 + sb;
#pragma unroll
    for (int e = 0; e < 4; e++) {
      __hip_atomic_store(aS + e, Pf[e], __ATOMIC_RELAXED, __HIP_MEMORY_SCOPE_AGENT);
      __hip_atomic_store(cS + e, Hf[e], __ATOMIC_RELAXED, __HIP_MEMORY_SCOPE_AGENT);
    }
  }
  __syncthreads();                                 // all payload stores drained (vmcnt 0)
  if (t == 0)
    __hip_atomic_store(flg + ticket, 1u, __ATOMIC_RELEASE, __HIP_MEMORY_SCOPE_AGENT);

  // 2) walk back: single flag per hop (uniform, wave-coalesced poll)
  if (!firstHalf) {
    f32x4 cA = {1.f, 1.f, 1.f, 1.f};
    f32x4 cC = {0.f, 0.f, 0.f, 0.f};
    f32x4 carry;
    bool resolved = false;
    int i = cs - 1;
    while (i >= 0 && !resolved) {
      const int ptk = i * NGRP + g;
      unsigned f = 0;
      int guard = 0;
      for (;;) {
        f = __hip_atomic_load(flg + ptk, __ATOMIC_ACQUIRE, __HIP_MEMORY_SCOPE_AGENT);
        if (f != 0u || ++guard > LOOKBACK_LIM) break;
        __builtin_amdgcn_s_sleep(2);
      }
      if (f == 2u) {                               // inclusive prefix available: finish
        const float* pS = pfxH + (size_t)ptk * 512 + sb;
#pragma unroll
        for (int e = 0; e < 4; e++) {
          const float hp = __hip_atomic_load(pS + e, __ATOMIC_RELAXED, __HIP_MEMORY_SCOPE_AGENT);
          carry[e] = fmaf(cA[e], hp, cC[e]);
        }
        resolved = true;
      } else if (f == 1u) {                        // aggregate: fold, keep walking
        const float* aP = aggA + (size_t)ptk * 512 + sb;
        const float* cP = aggC + (size_t)ptk * 512 + sb;
#pragma unroll
        for (int e = 0; e < 4; e++) {
          const float Ai = __hip_atomic_load(aP + e, __ATOMIC_RELAXED, __HIP_MEMORY_SCOPE_AGENT);
          const float Ci = __hip_atomic_load(cP + e, __ATOMIC_RELAXED, __HIP_MEMORY_SCOPE_AGENT);
          cC[e] = fmaf(cA[e], Ci, cC[e]);
          cA[e] *= Ai;
        }
        --i;
      } else {
        break;                                     // guard trip (should never happen)
      }
    }
    if (!resolved) carry = cC;                     // reached chunk 0: h_init = 0

    // 3) publish inclusive prefix + share carry with the other half via LDS
    float* pS = pfxH + (size_t)ticket * 512 + sb;
#pragma unroll
    for (int e = 0; e < 4; e++) {
      __hip_atomic_store(pS + e, fmaf(Pf[e], carry[e], Hf[e]),
                         __ATOMIC_RELAXED, __HIP_MEMORY_SCOPE_AGENT);
      cr[crb + e] = carry[e];
    }
  }
  __syncthreads();                                 // prefix stores + cr drained
  if (t == 0)
    __hip_atomic_store(flg + ticket, 2u, __ATOMIC_RELEASE, __HIP_MEMORY_SCOPE_AGENT);

  f32x4 cl;
#pragma unroll
  for (int e = 0; e < 4; e++) cl[e] = cr[crb + e];

  // out = o * (H_local + P_local * carry), fp32, direct
#pragma unroll
  for (int mi = 0; mi < 4; mi++) {
    const f32x4 hg = acc[mi][0] + acc[mi][1] * cl;
    const f32x4 ov = acc[mi][2] * hg;
    float* ob = out + (size_t)(m0 + wm + mi * 16 + lm) * (2 * HID) + dir * HID + hcol0;
    __builtin_nontemporal_store(ov, (f32x4*)ob);
  }
}

extern "C" void kernel_launch(void* const* d_in, const int* in_sizes, int n_in,
                              void* d_out, int out_size, void* d_ws, size_t ws_size,
                              hipStream_t stream) {
  const float* X   = (const float*)d_in[0];
  const float* Wfw = (const float*)d_in[1];
  const float* bfw = (const float*)d_in[2];
  const float* Wbw = (const float*)d_in[3];
  const float* bbw = (const float*)d_in[4];
  float* out = (float*)d_out;

  char* ws = (char*)d_ws;
  const size_t XB   = (size_t)MROWS * KDIM * 2;            // 32 MiB
  const size_t WB   = (size_t)2 * 3 * HID * KDIM * 2;      // 3 MiB
  const size_t SLAB = (size_t)NCH * NGRP * 512 * 4;        // 16 MiB each
  u16*      Xb   = (u16*)ws;
  u16*      Wb   = (u16*)(ws + XB);
  float*    aggA = (float*)(ws + XB + WB);
  float*    aggC = (float*)(ws + XB + WB + SLAB);
  float*    pfxH = (float*)(ws + XB + WB + 2 * SLAB);
  unsigned* flg  = (unsigned*)(ws + XB + WB + 3 * SLAB);   // 32 KiB
  int*      cnt  = (int*)(ws + XB + WB + 3 * SLAB + (size_t)NCH * NGRP * 4);

  // zero flags + ticket counter (tiny)
  hipMemsetAsync(flg, 0, (size_t)NCH * NGRP * 4 + 256, stream);

  // bf16 conversions (X + both W) in one launch
  cvt_all<<<17920, 256, 0, stream>>>(X, Wfw, Wbw, Xb, Wb);

  // fully fused GEMM + gates + scan + output: 8192 ticket-ordered blocks
  gemm_fused_scan<<<NCH * NGRP, 256, 0, stream>>>(Xb, Wb, bfw, bbw, out,
                                                  aggA, aggC, pfxH, flg, cnt);
}

// Round 6
// 385.404 us; speedup vs baseline: 18.9857x; 4.5493x over previous
//
#include <hip/hip_runtime.h>
#include <hip/hip_bf16.h>
#include <hip/hip_fp16.h>

// Problem dims
#define SEQ   2048
#define BATCH 16
#define DIN   512
#define HID   512
#define MROWS (SEQ*BATCH)   // 32768 GEMM rows (s,b)
#define KDIM  DIN           // 512

// Chunking: one 128-row m-tile = 8 timesteps x 16 batches = one scan chunk
#define NCH  256            // chunks along S (SEQ/8)
#define NSEQ (2*BATCH*HID)  // 16384 independent recurrences

typedef unsigned short u16;
typedef __bf16 bf16x8 __attribute__((ext_vector_type(8)));
typedef float  f32x4  __attribute__((ext_vector_type(4)));

__device__ __forceinline__ unsigned f2bf(float x) {
  unsigned u = __float_as_uint(x);
  return (u + 0x7fffu + ((u >> 16) & 1u)) >> 16;   // RNE
}

__device__ __forceinline__ unsigned pkh(float a, float b) {
  __half2 h = __floats2half2_rn(a, b);
  return *(const unsigned*)&h;
}
__device__ __forceinline__ float2 uph(unsigned x) {
  __half2 h = *(const __half2*)&x;
  return __half22float2(h);
}

__device__ __forceinline__ void async_ld16(const void* g, void* l) {
  __builtin_amdgcn_global_load_lds(
      (const __attribute__((address_space(1))) void*)g,
      (__attribute__((address_space(3))) void*)l, 16, 0, 0);
}

__device__ __forceinline__ float sig_fast(float x) {
  return __builtin_amdgcn_rcpf(1.f + __expf(-x));
}
__device__ __forceinline__ float tanh_fast(float x) {
  return 1.f - 2.f * __builtin_amdgcn_rcpf(1.f + __expf(2.f * x));
}

// ---- merged fp32 -> bf16 conversion: X (16384 blocks), Wfw (768), Wbw (768) ----
__global__ void cvt_all(const float* __restrict__ X, const float* __restrict__ Wfw,
                        const float* __restrict__ Wbw,
                        u16* __restrict__ Xb, u16* __restrict__ Wb) {
  const int tid = threadIdx.x;
  const int bid = blockIdx.x;
  const float* src; u16* dst; int idx;
  if (bid < 16384)      { src = X;   dst = Xb;                  idx = bid * 256 + tid; }
  else if (bid < 17152) { src = Wfw; dst = Wb;                  idx = (bid - 16384) * 256 + tid; }
  else                  { src = Wbw; dst = Wb + 3 * HID * KDIM; idx = (bid - 17152) * 256 + tid; }
  const float4 v = ((const float4*)src)[idx];
  uint2 r;
  r.x = f2bf(v.x) | (f2bf(v.y) << 16);
  r.y = f2bf(v.z) | (f2bf(v.w) << 16);
  ((uint2*)dst)[idx] = r;
}

// ---- Fused GEMM + bias + activation + intra-chunk scan epilogue ----
// (verified round-3 kernel: 154 us, VGPR 52, 4-5 blocks/CU)
// Block: 128 m-rows (8 s x 16 b) x 96 n-cols = all 3 gates for a 32-h tile of
// one direction.  Wave (2m x 2p): 64 m x 48 n; frag ni = gate.
// Epilogue: in-lane 4-step scan + cross-wave LDS exchange -> per-step prefixes
// (H,P); writes u = o*H, v = o*P (fp16, dir-sliced) and chunk (A,C) fp32.
__launch_bounds__(256, 4)
__global__ void gemm_fused(const u16* __restrict__ A, const u16* __restrict__ B,
                           const float* __restrict__ bfw, const float* __restrict__ bbw,
                           u16* __restrict__ U, u16* __restrict__ V,
                           float* __restrict__ ACn)
{
  __shared__ __align__(16) u16 sA[128 * 64];   // 16 KB
  __shared__ __align__(16) u16 sB[96 * 64];    // 12 KB

  const int t    = threadIdx.x;
  const int wave = t >> 6;
  const int lane = t & 63;
  const int m0  = blockIdx.y * 128;
  const int dir = blockIdx.x >> 4;
  const int hb  = (blockIdx.x & 15) * 32;
  const int wm  = (wave >> 1) * 64;   // m half
  const int p   = wave & 1;           // n half (h-sub-tile of 16)
  const int wn  = p * 48;

  f32x4 acc[4][3] = {};

  // staging: lane -> (rloc = lane>>3, c = lane&7); global 16B chunk g = c ^ rloc
  const int rloc = lane >> 3;
  const int gch  = (lane & 7) ^ rloc;
  const u16* gA  = A + (size_t)(m0 + wave * 32 + rloc) * KDIM + gch * 8;
  const u16* WbD = B + (size_t)dir * (3 * HID * KDIM);
  unsigned gBo[3];
#pragma unroll
  for (int j = 0; j < 3; j++) {
    const int nl = wave * 24 + j * 8 + rloc;      // 0..95
    const int pp = nl >= 48 ? 1 : 0;
    const int r  = nl - pp * 48;
    const int wrow = (r >> 4) * HID + hb + pp * 16 + (r & 15);
    gBo[j] = (unsigned)(wrow * KDIM + gch * 8);
  }

  const int lm = lane & 15;            // fragment index (= batch b for A rows)
  const int q  = lane >> 4;            // k-quad / n-reg group
  const int xs = lm & 7;               // read-side swizzle = row&7

  for (int kt = 0; kt < KDIM; kt += 64) {
    __syncthreads();
#pragma unroll
    for (int j = 0; j < 4; j++)
      async_ld16(gA + kt + (size_t)(j * 8) * KDIM, sA + (wave * 32 + j * 8) * 64);
#pragma unroll
    for (int j = 0; j < 3; j++)
      async_ld16(WbD + gBo[j] + kt, sB + (wave * 24 + j * 8) * 64);
    __syncthreads();

#pragma unroll
    for (int s = 0; s < 2; s++) {
      const int cofs = ((s * 4 + q) ^ xs) * 8;
      bf16x8 af[4], bfr[3];
#pragma unroll
      for (int mi = 0; mi < 4; mi++)
        af[mi] = *(const bf16x8*)(sA + (wm + mi * 16 + lm) * 64 + cofs);
#pragma unroll
      for (int ni = 0; ni < 3; ni++)
        bfr[ni] = *(const bf16x8*)(sB + (wn + ni * 16 + lm) * 64 + cofs);
#pragma unroll
      for (int mi = 0; mi < 4; mi++)
#pragma unroll
        for (int ni = 0; ni < 3; ni++)  // swapped: D col=lane&15 (m), row=q*4+i (n)
          acc[mi][ni] = __builtin_amdgcn_mfma_f32_16x16x32_bf16(bfr[ni], af[mi], acc[mi][ni], 0, 0, 0);
    }
  }

  // ---- epilogue ----
  // lane holds: m = m0 + wm + mi*16 + lm  (b = lm, s_local = (wave>>1)*4 + mi)
  //             h = hb + p*16 + q*4 + e, gate = ni
  const float* bias = dir ? bbw : bfw;
  const int hcol0 = hb + p * 16 + q * 4;

  const float4 t0 = *(const float4*)(bias + 0 * HID + hcol0);
  const float4 t1 = *(const float4*)(bias + 1 * HID + hcol0);
  const float4 t2 = *(const float4*)(bias + 2 * HID + hcol0);
  f32x4 bz, bff, bo;
  bz[0] = t0.x; bz[1] = t0.y; bz[2] = t0.z; bz[3] = t0.w;
  bff[0] = t1.x; bff[1] = t1.y; bff[2] = t1.z; bff[3] = t1.w;
  bo[0] = t2.x; bo[1] = t2.y; bo[2] = t2.z; bo[3] = t2.w;

  // activations in place: acc[mi][0] = c = f*z ; acc[mi][1] = a = 1-f ; acc[mi][2] = o
#pragma unroll
  for (int mi = 0; mi < 4; mi++)
#pragma unroll
    for (int e = 0; e < 4; e++) {
      const float z = tanh_fast(acc[mi][0][e] + bz[e]);
      const float f = sig_fast(acc[mi][1][e] + bff[e]);
      const float o = sig_fast(acc[mi][2][e] + bo[e]);
      acc[mi][0][e] = f * z;
      acc[mi][1][e] = 1.f - f;
      acc[mi][2][e] = o;
    }

  // in-lane 4-step scan in TIME order (fw: mi 0->3, bw: mi 3->0), in place:
  // acc[mi][0] <- H_step(mi), acc[mi][1] <- P_step(mi)   (static indices only)
#define SCAN_STEP(MI) { const f32x4 a_ = acc[MI][1], c_ = acc[MI][0]; \
    Hc = a_ * Hc + c_; Pc = a_ * Pc; acc[MI][0] = Hc; acc[MI][1] = Pc; }
  {
    f32x4 Hc = {0.f, 0.f, 0.f, 0.f}, Pc = {1.f, 1.f, 1.f, 1.f};
    if (!dir) { SCAN_STEP(0) SCAN_STEP(1) SCAN_STEP(2) SCAN_STEP(3) }
    else      { SCAN_STEP(3) SCAN_STEP(2) SCAN_STEP(1) SCAN_STEP(0) }
  }
#undef SCAN_STEP

  // cross-wave combine: time-first half publishes its 4-step (P,H); the other
  // half prefixes with it.  fw: first = wm-half 0 (s_local 0..3); bw: wm-half 1.
  __syncthreads();                       // all K-loop LDS reads done -> reuse sA
  f32x4* ex = (f32x4*)sA;                // [2p][64 lanes][2] = 4 KB
  const int slot = p * 64 + lane;
  const bool firstHalf = ((wave >> 1) == (dir ? 1 : 0));
  if (firstHalf) {
    ex[slot * 2 + 0] = dir ? acc[0][1] : acc[3][1];   // P
    ex[slot * 2 + 1] = dir ? acc[0][0] : acc[3][0];   // H
  }
  __syncthreads();
  if (!firstHalf) {
    const f32x4 P0 = ex[slot * 2 + 0];
    const f32x4 H0 = ex[slot * 2 + 1];
#pragma unroll
    for (int mi = 0; mi < 4; mi++) {
      acc[mi][0] = acc[mi][0] + acc[mi][1] * H0;
      acc[mi][1] = acc[mi][1] * P0;
    }
  }

  // u = o*H_prefix, v = o*P_prefix  -> fp16, dir-sliced buffers
  const size_t mrowbase = ((size_t)dir * MROWS + (size_t)(m0 + wm + lm)) * HID + hcol0;
#pragma unroll
  for (int mi = 0; mi < 4; mi++) {
    const f32x4 u = acc[mi][2] * acc[mi][0];
    const f32x4 v = acc[mi][2] * acc[mi][1];
    uint2 up, vp;
    up.x = pkh(u[0], u[1]); up.y = pkh(u[2], u[3]);
    vp.x = pkh(v[0], v[1]); vp.y = pkh(v[2], v[3]);
    *(uint2*)(U + mrowbase + (size_t)mi * 16 * HID) = up;
    *(uint2*)(V + mrowbase + (size_t)mi * 16 * HID) = vp;
  }

  // chunk summary from the time-LAST half (full-chunk prefix after fixup)
  if (!firstHalf) {
    const int ct = dir ? (NCH - 1 - (int)blockIdx.y) : (int)blockIdx.y;
    float* ACc = ACn + (size_t)ct * (2 * NSEQ) + (size_t)(dir * 16 + lm) * 512 + hcol0;
    const f32x4 Pf = dir ? acc[0][1] : acc[3][1];
    const f32x4 Hf = dir ? acc[0][0] : acc[3][0];
    *(f32x4*)(ACc)        = Pf;   // A_chunk
    *(f32x4*)(ACc + NSEQ) = Hf;   // C_chunk
  }
}

// ---- chunk combine: sequential over 256 chunks -> carry-in per chunk ----
// Latency-bound (64 blocks only): batch 16 chunks of loads (32 in flight)
// before the serial fma chain, so latency is paid once per 16 iterations.
__global__ void scan_combine(const float* __restrict__ ACn, float* __restrict__ Hin) {
  const int sidx = blockIdx.x * 256 + threadIdx.x;   // 16384 threads
  float carry = 0.f;
  for (int ct0 = 0; ct0 < NCH; ct0 += 16) {
    float Aa[16], Cc[16];
#pragma unroll
    for (int u = 0; u < 16; u++) {
      const size_t base = (size_t)(ct0 + u) * (2 * NSEQ) + sidx;
      Aa[u] = ACn[base];
      Cc[u] = ACn[base + NSEQ];
    }
#pragma unroll
    for (int u = 0; u < 16; u++) {
      Hin[(size_t)(ct0 + u) * NSEQ + sidx] = carry;
      carry = fmaf(Aa[u], carry, Cc[u]);
    }
  }
}

// ---- output: out = u + v * h_in  (pure fma stream, 8 h per thread) ----
__global__ void scan_out(const u16* __restrict__ U, const u16* __restrict__ V,
                         const float* __restrict__ Hin, float* __restrict__ out) {
  const int tid = blockIdx.x * 256 + threadIdx.x;    // 524288 total
  const int h   = (tid & 63) * 8;
  const int ct  = (tid >> 6) & 255;
  const int b   = (tid >> 14) & 15;
  const int dir = tid >> 18;
  const int sidx = (dir * BATCH + b) * HID + h;
  const float4 hv0 = *(const float4*)&Hin[(size_t)ct * NSEQ + sidx];
  const float4 hv1 = *(const float4*)&Hin[(size_t)ct * NSEQ + sidx + 4];
#pragma unroll
  for (int i = 0; i < 8; i++) {
    const int ts = ct * 8 + i;
    const int s  = dir ? (SEQ - 1 - ts) : ts;
    const size_t off = ((size_t)dir * MROWS + (size_t)s * BATCH + b) * HID + h;
    const uint4 uu = *(const uint4*)(U + off);
    const uint4 vv = *(const uint4*)(V + off);
    const float2 u0 = uph(uu.x), u1 = uph(uu.y), u2 = uph(uu.z), u3 = uph(uu.w);
    const float2 v0 = uph(vv.x), v1 = uph(vv.y), v2 = uph(vv.z), v3 = uph(vv.w);
    f32x4 o0, o1;
    o0[0] = fmaf(v0.x, hv0.x, u0.x);
    o0[1] = fmaf(v0.y, hv0.y, u0.y);
    o0[2] = fmaf(v1.x, hv0.z, u1.x);
    o0[3] = fmaf(v1.y, hv0.w, u1.y);
    o1[0] = fmaf(v2.x, hv1.x, u2.x);
    o1[1] = fmaf(v2.y, hv1.y, u2.y);
    o1[2] = fmaf(v3.x, hv1.z, u3.x);
    o1[3] = fmaf(v3.y, hv1.w, u3.y);
    float* ob = &out[((size_t)s * BATCH + b) * (2 * HID) + (size_t)dir * HID + h];
    __builtin_nontemporal_store(o0, (f32x4*)ob);
    __builtin_nontemporal_store(o1, (f32x4*)(ob + 4));
  }
}

extern "C" void kernel_launch(void* const* d_in, const int* in_sizes, int n_in,
                              void* d_out, int out_size, void* d_ws, size_t ws_size,
                              hipStream_t stream) {
  const float* X   = (const float*)d_in[0];
  const float* Wfw = (const float*)d_in[1];
  const float* bfw = (const float*)d_in[2];
  const float* Wbw = (const float*)d_in[3];
  const float* bbw = (const float*)d_in[4];
  float* out = (float*)d_out;

  char* ws = (char*)d_ws;
  const size_t XB  = (size_t)MROWS * KDIM * 2;          // 32 MiB
  const size_t WB  = (size_t)2 * 3 * HID * KDIM * 2;    // 3 MiB
  const size_t UVB = (size_t)2 * MROWS * HID * 2;       // 64 MiB each (2 dirs)
  u16*   Xb  = (u16*)ws;
  u16*   Wb  = (u16*)(ws + XB);
  u16*   U   = (u16*)(ws + XB + WB);
  u16*   V   = (u16*)(ws + XB + WB + UVB);
  float* ACn = (float*)(ws + XB + WB + 2 * UVB);        // 32 MiB
  float* Hin = ACn + (size_t)NCH * 2 * NSEQ;            // 16 MiB

  // bf16 conversions (X + both W) in one launch
  cvt_all<<<17920, 256, 0, stream>>>(X, Wfw, Wbw, Xb, Wb);

  // fused gates GEMM + intra-chunk scan: grid 32 (16 h-tiles x 2 dirs) x 256 m-tiles
  dim3 gg(32, 256);
  gemm_fused<<<gg, 256, 0, stream>>>(Xb, Wb, bfw, bbw, U, V, ACn);

  // chunk carry combine (256 chunks, 16384 sequences, load-batched)
  scan_combine<<<NSEQ / 256, 256, 0, stream>>>(ACn, Hin);

  // output pass (8 h per thread)
  scan_out<<<(2 * BATCH * NCH * 64) / 256, 256, 0, stream>>>(U, V, Hin, out);
}